// Round 1
// baseline (500.487 us; speedup 1.0000x reference)
//
#include <hip/hip_runtime.h>

#define TSTEPS 32
#define HID 1024
#define NCLS 10
#define BATCH 8
#define HDIM 1024
#define WDIM 2048
#define GGRP 32            // HDIM / TSTEPS
#define MROWS 8192         // BATCH*HDIM
#define KDIM 2048          // WDIM

// ---------------- 1x1 conv over 4 antenna channels ----------------
__global__ __launch_bounds__(256) void conv_kernel(
    const float4* __restrict__ x, const float* __restrict__ cw,
    const float* __restrict__ cb, float* __restrict__ xf)
{
    int p = blockIdx.x * 256 + threadIdx.x;   // one pixel per thread, 16,777,216 total
    float4 a = x[p];
    xf[p] = a.x * cw[0] + a.y * cw[1] + a.z * cw[2] + a.w * cw[3] + cb[0];
}

// ---------------- fp32 GEMM: C[M][N] = A[M][K] * Bw[N][K]^T + bias ----------------
#define BM 128
#define BN 128
#define BK 32
#define LDT 132   // padded LDS row stride (floats); 132*4=528 bytes, 16B aligned

__global__ __launch_bounds__(256) void gemm_kernel(
    const float* __restrict__ A,    // xf [MROWS][KDIM]
    const float* __restrict__ Bw,   // w1 [HID][KDIM]
    const float* __restrict__ bias, // b1 [HID]
    float* __restrict__ C)          // h  [MROWS][HID]
{
    __shared__ float As[BK * LDT];
    __shared__ float Bs[BK * LDT];
    const int tid = threadIdx.x;
    const int tx = tid & 15;
    const int ty = tid >> 4;
    const long rowA0 = (long)blockIdx.y * BM;
    const long colB0 = (long)blockIdx.x * BN;

    float acc[8][8];
#pragma unroll
    for (int i = 0; i < 8; ++i)
#pragma unroll
        for (int j = 0; j < 8; ++j) acc[i][j] = 0.f;

    for (int k0 = 0; k0 < KDIM; k0 += BK) {
        // stage A,B tiles (transposed into [BK][BM] with pad)
#pragma unroll
        for (int j = 0; j < 4; ++j) {
            int f  = tid + j * 256;
            int r  = f >> 3;            // 0..127
            int c4 = (f & 7) << 2;      // 0,4,...,28
            float4 av = *(const float4*)(A  + (rowA0 + r) * KDIM + k0 + c4);
            float4 bv = *(const float4*)(Bw + (colB0 + r) * KDIM + k0 + c4);
            As[(c4 + 0) * LDT + r] = av.x;
            As[(c4 + 1) * LDT + r] = av.y;
            As[(c4 + 2) * LDT + r] = av.z;
            As[(c4 + 3) * LDT + r] = av.w;
            Bs[(c4 + 0) * LDT + r] = bv.x;
            Bs[(c4 + 1) * LDT + r] = bv.y;
            Bs[(c4 + 2) * LDT + r] = bv.z;
            Bs[(c4 + 3) * LDT + r] = bv.w;
        }
        __syncthreads();
#pragma unroll
        for (int kk = 0; kk < BK; ++kk) {
            float4 a0 = *(const float4*)(As + kk * LDT + ty * 4);
            float4 a1 = *(const float4*)(As + kk * LDT + 64 + ty * 4);
            float4 b0 = *(const float4*)(Bs + kk * LDT + tx * 4);
            float4 b1 = *(const float4*)(Bs + kk * LDT + 64 + tx * 4);
            float av[8] = {a0.x, a0.y, a0.z, a0.w, a1.x, a1.y, a1.z, a1.w};
            float bv[8] = {b0.x, b0.y, b0.z, b0.w, b1.x, b1.y, b1.z, b1.w};
#pragma unroll
            for (int i = 0; i < 8; ++i)
#pragma unroll
                for (int j = 0; j < 8; ++j)
                    acc[i][j] += av[i] * bv[j];
        }
        __syncthreads();
    }
    // epilogue: bias + store
#pragma unroll
    for (int i = 0; i < 8; ++i) {
        int ro = (i < 4) ? (ty * 4 + i) : (64 + ty * 4 + (i - 4));
        long row = rowA0 + ro;
#pragma unroll
        for (int jh = 0; jh < 2; ++jh) {
            int co = jh * 64 + tx * 4;
            float4 v;
            v.x = acc[i][jh * 4 + 0] + bias[colB0 + co + 0];
            v.y = acc[i][jh * 4 + 1] + bias[colB0 + co + 1];
            v.z = acc[i][jh * 4 + 2] + bias[colB0 + co + 2];
            v.w = acc[i][jh * 4 + 3] + bias[colB0 + co + 3];
            *(float4*)(C + row * HID + colB0 + co) = v;
        }
    }
}

// ---------------- leaky scan over T (layer 1) + spike-count ----------------
__global__ __launch_bounds__(256) void scan1_kernel(
    const float* __restrict__ h, const float* __restrict__ beta1,
    const float* __restrict__ thr1, float* __restrict__ s)
{
    int n  = blockIdx.x * 256 + threadIdx.x;  // (b*32+g)*1024 + d, 262144 total
    int bg = n >> 10;
    int d  = n & 1023;
    float b  = fminf(fmaxf(beta1[0], 0.f), 1.f);
    float th = thr1[0];
    const float* p = h + (size_t)bg * TSTEPS * HID + d;
    float mem = 0.f, cnt = 0.f;
#pragma unroll
    for (int t = 0; t < TSTEPS; ++t) {
        mem = b * mem + p[(size_t)t * HID];
        float spk = mem > th ? 1.f : 0.f;
        mem -= spk * th;
        cnt += spk;
    }
    s[n] = cnt;
}

// ---------------- FC2: h2[bg][c] = s[bg][:] . w2[c][:] + b2[c] ----------------
__global__ __launch_bounds__(256) void fc2_kernel(
    const float* __restrict__ s, const float* __restrict__ w2,
    const float* __restrict__ b2, float* __restrict__ h2)
{
    int bg  = blockIdx.x;     // 0..255
    int tid = threadIdx.x;
    const float* sp = s + (size_t)bg * HID;
    float part[NCLS];
#pragma unroll
    for (int c = 0; c < NCLS; ++c) part[c] = 0.f;
    for (int d = tid; d < HID; d += 256) {
        float sv = sp[d];
#pragma unroll
        for (int c = 0; c < NCLS; ++c) part[c] += sv * w2[c * HID + d];
    }
#pragma unroll
    for (int c = 0; c < NCLS; ++c)
        for (int off = 32; off > 0; off >>= 1)
            part[c] += __shfl_down(part[c], off, 64);
    __shared__ float red[NCLS][4];
    int wave = tid >> 6, lane = tid & 63;
    if (lane == 0)
#pragma unroll
        for (int c = 0; c < NCLS; ++c) red[c][wave] = part[c];
    __syncthreads();
    if (tid < NCLS) {
        float v = red[tid][0] + red[tid][1] + red[tid][2] + red[tid][3] + b2[tid];
        h2[bg * NCLS + tid] = v;
    }
}

// ---------------- leaky scan over G (layer 2) + logits + softmax ----------------
__global__ __launch_bounds__(128) void scan2_kernel(
    const float* __restrict__ h2, const float* __restrict__ beta2,
    const float* __restrict__ thr2, float* __restrict__ out)
{
    __shared__ float logits[BATCH][NCLS];
    int t = threadIdx.x;
    if (t < BATCH * NCLS) {
        int b = t / NCLS, c = t % NCLS;
        float bb = fminf(fmaxf(beta2[0], 0.f), 1.f);
        float th = thr2[0];
        float mem = 0.f, lg = 0.f;
        for (int g = 0; g < GGRP; ++g) {
            float u = h2[(b * GGRP + g) * NCLS + c];
            mem = bb * mem + u;
            float spk = mem > th ? 1.f : 0.f;
            mem -= spk * th;
            lg += spk;
        }
        logits[b][c] = lg;
    }
    __syncthreads();
    if (t < BATCH) {
        float mx = -1e30f;
        for (int c = 0; c < NCLS; ++c) mx = fmaxf(mx, logits[t][c]);
        float e[NCLS];
        float sum = 0.f;
        for (int c = 0; c < NCLS; ++c) { e[c] = expf(logits[t][c] - mx); sum += e[c]; }
        for (int c = 0; c < NCLS; ++c) out[t * NCLS + c] = e[c] / sum;
    }
}

extern "C" void kernel_launch(void* const* d_in, const int* in_sizes, int n_in,
                              void* d_out, int out_size, void* d_ws, size_t ws_size,
                              hipStream_t stream)
{
    const float* x     = (const float*)d_in[0];
    const float* cw    = (const float*)d_in[1];
    const float* cb    = (const float*)d_in[2];
    const float* w1    = (const float*)d_in[3];
    const float* b1    = (const float*)d_in[4];
    const float* beta1 = (const float*)d_in[5];
    const float* thr1  = (const float*)d_in[6];
    const float* w2    = (const float*)d_in[7];
    const float* b2    = (const float*)d_in[8];
    const float* beta2 = (const float*)d_in[9];
    const float* thr2  = (const float*)d_in[10];
    float* out = (float*)d_out;

    // workspace layout (fp32): xf 64MB | h 32MB | s 1MB | h2 10KB  (~97.3MB total)
    float* xf = (float*)d_ws;                          // 16,777,216 floats
    float* h  = xf + (size_t)MROWS * KDIM;             //  8,388,608 floats
    float* s  = h  + (size_t)MROWS * HID;              //    262,144 floats
    float* h2 = s  + (size_t)BATCH * GGRP * HID;       //      2,560 floats

    conv_kernel <<<65536, 256, 0, stream>>>((const float4*)x, cw, cb, xf);
    gemm_kernel <<<dim3(8, 64), 256, 0, stream>>>(xf, w1, b1, h);
    scan1_kernel<<<1024, 256, 0, stream>>>(h, beta1, thr1, s);
    fc2_kernel  <<<256, 256, 0, stream>>>(s, w2, b2, h2);
    scan2_kernel<<<1, 128, 0, stream>>>(h2, beta2, thr2, out);
}

// Round 2
// 197.019 us; speedup vs baseline: 2.5403x; 2.5403x over previous
//
#include <hip/hip_runtime.h>

#define TSTEPS 32
#define HID 1024
#define NCLS 10
#define BATCH 8
#define GGRP 32            // groups = H / TSTEPS
#define MROWS 8192         // BATCH * 1024 rows of the big GEMM
#define GK 2048            // K dim (W)
#define GN 1024            // N dim (HIDDEN)
#define PITCH 40           // LDS row pitch in shorts (32 data + 8 pad = 80B, 16B aligned)

typedef __attribute__((ext_vector_type(8))) short bf16x8;
typedef __attribute__((ext_vector_type(4))) float f32x4;

__device__ __forceinline__ unsigned short bf16_rne(float v) {
    unsigned u = __builtin_bit_cast(unsigned, v);
    return (unsigned short)((u + 0x7FFFu + ((u >> 16) & 1u)) >> 16);
}
__device__ __forceinline__ float bf16_f(unsigned short h) {
    unsigned u = (unsigned)h << 16;
    return __builtin_bit_cast(float, u);
}

// ---------------- 1x1 conv -> bf16 hi/lo split of A ----------------
__global__ __launch_bounds__(256) void conv_split_kernel(
    const float4* __restrict__ x, const float* __restrict__ cw,
    const float* __restrict__ cb,
    unsigned short* __restrict__ ahi, unsigned short* __restrict__ alo)
{
    int p = blockIdx.x * 256 + threadIdx.x;   // 16,777,216 pixels
    float4 a = x[p];
    float v = a.x * cw[0] + a.y * cw[1] + a.z * cw[2] + a.w * cw[3] + cb[0];
    unsigned short h = bf16_rne(v);
    ahi[p] = h;
    alo[p] = bf16_rne(v - bf16_f(h));
}

// ---------------- w1 -> bf16 hi/lo split of B ----------------
__global__ __launch_bounds__(256) void wsplit_kernel(
    const float* __restrict__ w, unsigned short* __restrict__ whi,
    unsigned short* __restrict__ wlo)
{
    int p = blockIdx.x * 256 + threadIdx.x;   // 2,097,152 elems
    float v = w[p];
    unsigned short h = bf16_rne(v);
    whi[p] = h;
    wlo[p] = bf16_rne(v - bf16_f(h));
}

// ---------------- MFMA GEMM (3-term bf16 split) + fused leaky scan over T ----------------
// C[row][col] = A[row][:] . B[col][:] + b1[col]; rows = (b,g,t); block = 128 rows x 128 cols
// covers all 32 t for 4 (b,g) groups -> scan + spike-count fused, writes s directly.
__global__ __launch_bounds__(256) void gemm_scan_kernel(
    const unsigned short* __restrict__ Ahi, const unsigned short* __restrict__ Alo,
    const unsigned short* __restrict__ Bhi, const unsigned short* __restrict__ Blo,
    const float* __restrict__ bias,
    const float* __restrict__ beta1, const float* __restrict__ thr1,
    float* __restrict__ S)
{
    __shared__ __align__(16) unsigned short smem[4 * 128 * PITCH];  // 40,960 B
    unsigned short* sAhi = smem;
    unsigned short* sAlo = smem + 128 * PITCH;
    unsigned short* sBhi = smem + 2 * 128 * PITCH;
    unsigned short* sBlo = smem + 3 * 128 * PITCH;

    const int tid = threadIdx.x;
    const int row0 = blockIdx.y * 128;
    const int col0 = blockIdx.x * 128;
    const int wid = tid >> 6, lane = tid & 63;
    const int wr = wid >> 1, wc = wid & 1;        // wave -> 64x64 quadrant
    const int lm = lane & 15, lk = lane >> 4;

    // staging: 512 chunks of 16B per tile-pair half; thread does 2 chunks/tile
    const int r0 = tid >> 2, k0o = (tid & 3) * 8;
    const int r1 = (tid + 256) >> 2, k1o = ((tid + 256) & 3) * 8;

    const unsigned short* gAh0 = Ahi + (size_t)(row0 + r0) * GK + k0o;
    const unsigned short* gAh1 = Ahi + (size_t)(row0 + r1) * GK + k1o;
    const unsigned short* gAl0 = Alo + (size_t)(row0 + r0) * GK + k0o;
    const unsigned short* gAl1 = Alo + (size_t)(row0 + r1) * GK + k1o;
    const unsigned short* gBh0 = Bhi + (size_t)(col0 + r0) * GK + k0o;
    const unsigned short* gBh1 = Bhi + (size_t)(col0 + r1) * GK + k1o;
    const unsigned short* gBl0 = Blo + (size_t)(col0 + r0) * GK + k0o;
    const unsigned short* gBl1 = Blo + (size_t)(col0 + r1) * GK + k1o;

    unsigned short* wAh0 = sAhi + r0 * PITCH + k0o;
    unsigned short* wAh1 = sAhi + r1 * PITCH + k1o;
    unsigned short* wAl0 = sAlo + r0 * PITCH + k0o;
    unsigned short* wAl1 = sAlo + r1 * PITCH + k1o;
    unsigned short* wBh0 = sBhi + r0 * PITCH + k0o;
    unsigned short* wBh1 = sBhi + r1 * PITCH + k1o;
    unsigned short* wBl0 = sBlo + r0 * PITCH + k0o;
    unsigned short* wBl1 = sBlo + r1 * PITCH + k1o;

    f32x4 acc[4][4];
#pragma unroll
    for (int i = 0; i < 4; ++i)
#pragma unroll
        for (int j = 0; j < 4; ++j) acc[i][j] = (f32x4)0.f;

    for (int kk = 0; kk < GK; kk += 32) {
        bf16x8 vAh0 = *(const bf16x8*)gAh0;
        bf16x8 vAh1 = *(const bf16x8*)gAh1;
        bf16x8 vAl0 = *(const bf16x8*)gAl0;
        bf16x8 vAl1 = *(const bf16x8*)gAl1;
        bf16x8 vBh0 = *(const bf16x8*)gBh0;
        bf16x8 vBh1 = *(const bf16x8*)gBh1;
        bf16x8 vBl0 = *(const bf16x8*)gBl0;
        bf16x8 vBl1 = *(const bf16x8*)gBl1;
        *(bf16x8*)wAh0 = vAh0;  *(bf16x8*)wAh1 = vAh1;
        *(bf16x8*)wAl0 = vAl0;  *(bf16x8*)wAl1 = vAl1;
        *(bf16x8*)wBh0 = vBh0;  *(bf16x8*)wBh1 = vBh1;
        *(bf16x8*)wBl0 = vBl0;  *(bf16x8*)wBl1 = vBl1;
        __syncthreads();

        bf16x8 ah[4], al[4], bh[4], bl[4];
#pragma unroll
        for (int i = 0; i < 4; ++i) {
            ah[i] = *(const bf16x8*)(sAhi + (wr * 64 + i * 16 + lm) * PITCH + lk * 8);
            al[i] = *(const bf16x8*)(sAlo + (wr * 64 + i * 16 + lm) * PITCH + lk * 8);
            bh[i] = *(const bf16x8*)(sBhi + (wc * 64 + i * 16 + lm) * PITCH + lk * 8);
            bl[i] = *(const bf16x8*)(sBlo + (wc * 64 + i * 16 + lm) * PITCH + lk * 8);
        }
#pragma unroll
        for (int i = 0; i < 4; ++i)
#pragma unroll
            for (int j = 0; j < 4; ++j) {
                acc[i][j] = __builtin_amdgcn_mfma_f32_16x16x32_bf16(ah[i], bh[j], acc[i][j], 0, 0, 0);
                acc[i][j] = __builtin_amdgcn_mfma_f32_16x16x32_bf16(ah[i], bl[j], acc[i][j], 0, 0, 0);
                acc[i][j] = __builtin_amdgcn_mfma_f32_16x16x32_bf16(al[i], bh[j], acc[i][j], 0, 0, 0);
            }
        __syncthreads();

        gAh0 += 32; gAh1 += 32; gAl0 += 32; gAl1 += 32;
        gBh0 += 32; gBh1 += 32; gBl0 += 32; gBl1 += 32;
    }

    // ---- fused leaky scan over t (reuse LDS as [64][132] f32 buffer, 33,792B) ----
    float* sb = (float*)smem;
    const float bclamp = fminf(fmaxf(beta1[0], 0.f), 1.f);
    const float th = thr1[0];
    const int sbg = tid >> 7;          // 0..1 (bg within band)
    const int scol = tid & 127;        // 0..127
    const float bv = bias[col0 + scol];

#pragma unroll
    for (int band = 0; band < 2; ++band) {
        if (wr == band) {
#pragma unroll
            for (int i = 0; i < 4; ++i)
#pragma unroll
                for (int j = 0; j < 4; ++j)
#pragma unroll
                    for (int r = 0; r < 4; ++r)
                        sb[(i * 16 + lk * 4 + r) * 132 + wc * 64 + j * 16 + lm] = acc[i][j][r];
        }
        __syncthreads();
        float mem = 0.f, cnt = 0.f;
#pragma unroll
        for (int t = 0; t < TSTEPS; ++t) {
            float u = sb[(sbg * 32 + t) * 132 + scol] + bv;
            mem = bclamp * mem + u;
            float spk = mem > th ? 1.f : 0.f;
            mem -= spk * th;
            cnt += spk;
        }
        int bgg = (row0 >> 5) + band * 2 + sbg;
        S[(size_t)bgg * GN + col0 + scol] = cnt;
        __syncthreads();
    }
}

// ---------------- FC2 ----------------
__global__ __launch_bounds__(256) void fc2_kernel(
    const float* __restrict__ s, const float* __restrict__ w2,
    const float* __restrict__ b2, float* __restrict__ h2)
{
    int bg  = blockIdx.x;     // 0..255
    int tid = threadIdx.x;
    const float* sp = s + (size_t)bg * HID;
    float part[NCLS];
#pragma unroll
    for (int c = 0; c < NCLS; ++c) part[c] = 0.f;
    for (int d = tid; d < HID; d += 256) {
        float sv = sp[d];
#pragma unroll
        for (int c = 0; c < NCLS; ++c) part[c] += sv * w2[c * HID + d];
    }
#pragma unroll
    for (int c = 0; c < NCLS; ++c)
        for (int off = 32; off > 0; off >>= 1)
            part[c] += __shfl_down(part[c], off, 64);
    __shared__ float red[NCLS][4];
    int wave = tid >> 6, lanei = tid & 63;
    if (lanei == 0)
#pragma unroll
        for (int c = 0; c < NCLS; ++c) red[c][wave] = part[c];
    __syncthreads();
    if (tid < NCLS) {
        float v = red[tid][0] + red[tid][1] + red[tid][2] + red[tid][3] + b2[tid];
        h2[bg * NCLS + tid] = v;
    }
}

// ---------------- scan over G + softmax ----------------
__global__ __launch_bounds__(128) void scan2_kernel(
    const float* __restrict__ h2, const float* __restrict__ beta2,
    const float* __restrict__ thr2, float* __restrict__ out)
{
    __shared__ float logits[BATCH][NCLS];
    int t = threadIdx.x;
    if (t < BATCH * NCLS) {
        int b = t / NCLS, c = t % NCLS;
        float bb = fminf(fmaxf(beta2[0], 0.f), 1.f);
        float th = thr2[0];
        float mem = 0.f, lg = 0.f;
        for (int g = 0; g < GGRP; ++g) {
            float u = h2[(b * GGRP + g) * NCLS + c];
            mem = bb * mem + u;
            float spk = mem > th ? 1.f : 0.f;
            mem -= spk * th;
            lg += spk;
        }
        logits[b][c] = lg;
    }
    __syncthreads();
    if (t < BATCH) {
        float mx = -1e30f;
        for (int c = 0; c < NCLS; ++c) mx = fmaxf(mx, logits[t][c]);
        float e[NCLS];
        float sum = 0.f;
        for (int c = 0; c < NCLS; ++c) { e[c] = expf(logits[t][c] - mx); sum += e[c]; }
        for (int c = 0; c < NCLS; ++c) out[t * NCLS + c] = e[c] / sum;
    }
}

extern "C" void kernel_launch(void* const* d_in, const int* in_sizes, int n_in,
                              void* d_out, int out_size, void* d_ws, size_t ws_size,
                              hipStream_t stream)
{
    const float* x     = (const float*)d_in[0];
    const float* cw    = (const float*)d_in[1];
    const float* cb    = (const float*)d_in[2];
    const float* w1    = (const float*)d_in[3];
    const float* b1    = (const float*)d_in[4];
    const float* beta1 = (const float*)d_in[5];
    const float* thr1  = (const float*)d_in[6];
    const float* w2    = (const float*)d_in[7];
    const float* b2    = (const float*)d_in[8];
    const float* beta2 = (const float*)d_in[9];
    const float* thr2  = (const float*)d_in[10];
    float* out = (float*)d_out;

    // ws: ahi 33.5MB | alo 33.5MB | bhi 4.2MB | blo 4.2MB | s 1MB | h2 10KB  (~76.6MB)
    unsigned short* ahi = (unsigned short*)d_ws;
    unsigned short* alo = ahi + (size_t)MROWS * GK;
    unsigned short* bhi = alo + (size_t)MROWS * GK;
    unsigned short* blo = bhi + (size_t)GN * GK;
    float* s  = (float*)(blo + (size_t)GN * GK);
    float* h2 = s + (size_t)BATCH * GGRP * HID;

    conv_split_kernel<<<65536, 256, 0, stream>>>((const float4*)x, cw, cb, ahi, alo);
    wsplit_kernel    <<<8192, 256, 0, stream>>>(w1, bhi, blo);
    gemm_scan_kernel <<<dim3(8, 64), 256, 0, stream>>>(ahi, alo, bhi, blo, b1, beta1, thr1, s);
    fc2_kernel       <<<256, 256, 0, stream>>>(s, w2, b2, h2);
    scan2_kernel     <<<1, 128, 0, stream>>>(h2, beta2, thr2, out);
}

// Round 3
// 173.681 us; speedup vs baseline: 2.8816x; 1.1344x over previous
//
#include <hip/hip_runtime.h>

#define TSTEPS 32
#define HID 1024
#define NCLS 10
#define BATCH 8
#define GGRP 32            // groups = H / TSTEPS
#define MROWS 8192         // BATCH * 1024 rows of the big GEMM
#define GK 2048            // K dim (W)
#define GN 1024            // N dim (HIDDEN)

typedef __attribute__((ext_vector_type(8))) short bf16x8;
typedef __attribute__((ext_vector_type(4))) float f32x4;

__device__ __forceinline__ unsigned short bf16_rne(float v) {
    unsigned u = __builtin_bit_cast(unsigned, v);
    return (unsigned short)((u + 0x7FFFu + ((u >> 16) & 1u)) >> 16);
}
__device__ __forceinline__ float bf16_f(unsigned short h) {
    unsigned u = (unsigned)h << 16;
    return __builtin_bit_cast(float, u);
}
__device__ __forceinline__ void gload16(const unsigned short* g, unsigned short* l) {
    __builtin_amdgcn_global_load_lds(
        (const __attribute__((address_space(1))) void*)g,
        (__attribute__((address_space(3))) void*)l, 16, 0, 0);
}

// Packed tile format (both A and B): tile index (rb, kb); within a tile,
// chunk c = kc*128 + row holds 8 bf16 = M[rb*128+row][kb*32 + kc*8 .. +7].
// Tile = 512 chunks * 16B = 8KB. Linear chunk order == global_load_lds lane
// order == conflict-free ds_read_b128 fragment order.

// ---------------- 1x1 conv -> packed bf16 hi/lo A tiles ----------------
__global__ __launch_bounds__(256) void conv_pack_kernel(
    const float4* __restrict__ x, const float* __restrict__ cw,
    const float* __restrict__ cb,
    unsigned short* __restrict__ Ahi, unsigned short* __restrict__ Alo)
{
    const int rb = blockIdx.x >> 6;     // 0..63 row-block
    const int kb = blockIdx.x & 63;     // 0..63 k-block
    const float c0 = cw[0], c1 = cw[1], c2 = cw[2], c3 = cw[3], cbv = cb[0];
    const int tid = threadIdx.x;
#pragma unroll
    for (int cc = 0; cc < 2; ++cc) {
        int c = tid + cc * 256;         // chunk 0..511
        int kc = c >> 7, row = c & 127;
        const float4* px = x + ((size_t)(rb * 128 + row) * 2048 + kb * 32 + kc * 8);
        bf16x8 h8, l8;
#pragma unroll
        for (int e = 0; e < 8; ++e) {
            float4 a = px[e];
            float v = a.x * c0 + a.y * c1 + a.z * c2 + a.w * c3 + cbv;
            unsigned short h = bf16_rne(v);
            h8[e] = (short)h;
            l8[e] = (short)bf16_rne(v - bf16_f(h));
        }
        size_t off = ((size_t)blockIdx.x * 512 + c) * 8;
        *(bf16x8*)(Ahi + off) = h8;
        *(bf16x8*)(Alo + off) = l8;
    }
}

// ---------------- w1 -> packed bf16 hi/lo B tiles ----------------
__global__ __launch_bounds__(256) void wpack_kernel(
    const float* __restrict__ w, unsigned short* __restrict__ Bhi,
    unsigned short* __restrict__ Blo)
{
    const int kb = blockIdx.x & 63;     // blockIdx.x = cb*64 + kb, cb 0..7
    const int cbk = blockIdx.x >> 6;
    const int tid = threadIdx.x;
#pragma unroll
    for (int cc = 0; cc < 2; ++cc) {
        int c = tid + cc * 256;
        int kc = c >> 7, row = c & 127;
        const float* pw = w + ((size_t)(cbk * 128 + row) * 2048 + kb * 32 + kc * 8);
        bf16x8 h8, l8;
#pragma unroll
        for (int e = 0; e < 8; ++e) {
            float v = pw[e];
            unsigned short h = bf16_rne(v);
            h8[e] = (short)h;
            l8[e] = (short)bf16_rne(v - bf16_f(h));
        }
        size_t off = ((size_t)blockIdx.x * 512 + c) * 8;
        *(bf16x8*)(Bhi + off) = h8;
        *(bf16x8*)(Blo + off) = l8;
    }
}

// ---------------- MFMA GEMM (3-term bf16 split) + fused leaky scan ----------------
// 128x128 tile, BK=32, 4 waves (2x2 of 64x64), double-buffered LDS via
// global_load_lds width-16; 2-phase schedule: STAGE(k+1) issued before MFMA(k),
// single barrier per K-step drains it.
__global__ __launch_bounds__(256) void gemm_scan_kernel(
    const unsigned short* __restrict__ Ahi, const unsigned short* __restrict__ Alo,
    const unsigned short* __restrict__ Bhi, const unsigned short* __restrict__ Blo,
    const float* __restrict__ bias,
    const float* __restrict__ beta1, const float* __restrict__ thr1,
    float* __restrict__ S)
{
    // per buffer: Ahi[0..4095] Alo[4096..] Bhi[8192..] Blo[12288..] (shorts)
    __shared__ __align__(16) unsigned short smem[2][16384];   // 64 KB

    const int tid = threadIdx.x;
    const int lane = tid & 63, wv = tid >> 6;
    const int wr = wv >> 1, wc = wv & 1;          // wave quadrant
    const int lm = lane & 15, lk = lane >> 4;
    const int rb = blockIdx.y;                    // 0..63
    const int col0 = blockIdx.x * 128;

    const unsigned short* gAh = Ahi + (size_t)rb * (64 * 4096);
    const unsigned short* gAl = Alo + (size_t)rb * (64 * 4096);
    const unsigned short* gBh = Bhi + (size_t)blockIdx.x * (64 * 4096);
    const unsigned short* gBl = Blo + (size_t)blockIdx.x * (64 * 4096);

    f32x4 acc[4][4];
#pragma unroll
    for (int i = 0; i < 4; ++i)
#pragma unroll
        for (int j = 0; j < 4; ++j) acc[i][j] = (f32x4)0.f;

#define STAGE(buf, kb_)                                                          \
    {                                                                            \
        const size_t tb = (size_t)(kb_) * 4096;                                  \
        unsigned short* dst = &smem[buf][0];                                     \
        _Pragma("unroll")                                                        \
        for (int ii = 0; ii < 2; ++ii) {                                         \
            size_t so = tb + (size_t)(wv * 128 + ii * 64 + lane) * 8;            \
            int dl = (wv * 128 + ii * 64) * 8;                                   \
            gload16(gAh + so, dst + 0 + dl);                                     \
            gload16(gAl + so, dst + 4096 + dl);                                  \
            gload16(gBh + so, dst + 8192 + dl);                                  \
            gload16(gBl + so, dst + 12288 + dl);                                 \
        }                                                                        \
    }

    STAGE(0, 0);
    __syncthreads();

    int cur = 0;
    for (int kb = 0; kb < 64; ++kb) {
        if (kb < 63) STAGE(cur ^ 1, kb + 1);

        const unsigned short* bufp = &smem[cur][0];
        bf16x8 ah[4], al[4], bh[4], bl[4];
#pragma unroll
        for (int i = 0; i < 4; ++i) {
            int ca = lk * 128 + wr * 64 + i * 16 + lm;
            int cb2 = lk * 128 + wc * 64 + i * 16 + lm;
            ah[i] = *(const bf16x8*)(bufp + 0 + ca * 8);
            al[i] = *(const bf16x8*)(bufp + 4096 + ca * 8);
            bh[i] = *(const bf16x8*)(bufp + 8192 + cb2 * 8);
            bl[i] = *(const bf16x8*)(bufp + 12288 + cb2 * 8);
        }
#pragma unroll
        for (int i = 0; i < 4; ++i)
#pragma unroll
            for (int j = 0; j < 4; ++j) {
                acc[i][j] = __builtin_amdgcn_mfma_f32_16x16x32_bf16(ah[i], bh[j], acc[i][j], 0, 0, 0);
                acc[i][j] = __builtin_amdgcn_mfma_f32_16x16x32_bf16(ah[i], bl[j], acc[i][j], 0, 0, 0);
                acc[i][j] = __builtin_amdgcn_mfma_f32_16x16x32_bf16(al[i], bh[j], acc[i][j], 0, 0, 0);
            }
        __syncthreads();   // drains vmcnt(0): next buffer staged; everyone done reading cur
        cur ^= 1;
    }

    // ---- fused leaky scan over t (reuse LDS as [64][132] f32 buffer) ----
    float* sb = (float*)&smem[0][0];
    const float bclamp = fminf(fmaxf(beta1[0], 0.f), 1.f);
    const float th = thr1[0];
    const int sbg = tid >> 7;          // 0..1 (bg within band)
    const int scol = tid & 127;        // 0..127
    const float bv = bias[col0 + scol];

#pragma unroll
    for (int band = 0; band < 2; ++band) {
        if (wr == band) {
#pragma unroll
            for (int i = 0; i < 4; ++i)
#pragma unroll
                for (int j = 0; j < 4; ++j)
#pragma unroll
                    for (int r = 0; r < 4; ++r)
                        sb[(i * 16 + lk * 4 + r) * 132 + wc * 64 + j * 16 + lm] = acc[i][j][r];
        }
        __syncthreads();
        float mem = 0.f, cnt = 0.f;
#pragma unroll
        for (int t = 0; t < TSTEPS; ++t) {
            float u = sb[(sbg * 32 + t) * 132 + scol] + bv;
            mem = bclamp * mem + u;
            float spk = mem > th ? 1.f : 0.f;
            mem -= spk * th;
            cnt += spk;
        }
        int bgg = ((rb * 128) >> 5) + band * 2 + sbg;
        S[(size_t)bgg * GN + col0 + scol] = cnt;
        __syncthreads();
    }
}

// ---------------- FC2 ----------------
__global__ __launch_bounds__(256) void fc2_kernel(
    const float* __restrict__ s, const float* __restrict__ w2,
    const float* __restrict__ b2, float* __restrict__ h2)
{
    int bg  = blockIdx.x;     // 0..255
    int tid = threadIdx.x;
    const float* sp = s + (size_t)bg * HID;
    float part[NCLS];
#pragma unroll
    for (int c = 0; c < NCLS; ++c) part[c] = 0.f;
    for (int d = tid; d < HID; d += 256) {
        float sv = sp[d];
#pragma unroll
        for (int c = 0; c < NCLS; ++c) part[c] += sv * w2[c * HID + d];
    }
#pragma unroll
    for (int c = 0; c < NCLS; ++c)
        for (int off = 32; off > 0; off >>= 1)
            part[c] += __shfl_down(part[c], off, 64);
    __shared__ float red[NCLS][4];
    int wave = tid >> 6, lanei = tid & 63;
    if (lanei == 0)
#pragma unroll
        for (int c = 0; c < NCLS; ++c) red[c][wave] = part[c];
    __syncthreads();
    if (tid < NCLS) {
        float v = red[tid][0] + red[tid][1] + red[tid][2] + red[tid][3] + b2[tid];
        h2[bg * NCLS + tid] = v;
    }
}

// ---------------- scan over G + softmax ----------------
__global__ __launch_bounds__(128) void scan2_kernel(
    const float* __restrict__ h2, const float* __restrict__ beta2,
    const float* __restrict__ thr2, float* __restrict__ out)
{
    __shared__ float logits[BATCH][NCLS];
    int t = threadIdx.x;
    if (t < BATCH * NCLS) {
        int b = t / NCLS, c = t % NCLS;
        float bb = fminf(fmaxf(beta2[0], 0.f), 1.f);
        float th = thr2[0];
        float mem = 0.f, lg = 0.f;
        for (int g = 0; g < GGRP; ++g) {
            float u = h2[(b * GGRP + g) * NCLS + c];
            mem = bb * mem + u;
            float spk = mem > th ? 1.f : 0.f;
            mem -= spk * th;
            lg += spk;
        }
        logits[b][c] = lg;
    }
    __syncthreads();
    if (t < BATCH) {
        float mx = -1e30f;
        for (int c = 0; c < NCLS; ++c) mx = fmaxf(mx, logits[t][c]);
        float e[NCLS];
        float sum = 0.f;
        for (int c = 0; c < NCLS; ++c) { e[c] = expf(logits[t][c] - mx); sum += e[c]; }
        for (int c = 0; c < NCLS; ++c) out[t * NCLS + c] = e[c] / sum;
    }
}

extern "C" void kernel_launch(void* const* d_in, const int* in_sizes, int n_in,
                              void* d_out, int out_size, void* d_ws, size_t ws_size,
                              hipStream_t stream)
{
    const float* x     = (const float*)d_in[0];
    const float* cw    = (const float*)d_in[1];
    const float* cb    = (const float*)d_in[2];
    const float* w1    = (const float*)d_in[3];
    const float* b1    = (const float*)d_in[4];
    const float* beta1 = (const float*)d_in[5];
    const float* thr1  = (const float*)d_in[6];
    const float* w2    = (const float*)d_in[7];
    const float* b2    = (const float*)d_in[8];
    const float* beta2 = (const float*)d_in[9];
    const float* thr2  = (const float*)d_in[10];
    float* out = (float*)d_out;

    // ws: Ahi 32MB | Alo 32MB | Bhi 4MB | Blo 4MB | s 1MB | h2 10KB (~73MB)
    unsigned short* ahi = (unsigned short*)d_ws;
    unsigned short* alo = ahi + (size_t)MROWS * GK;
    unsigned short* bhi = alo + (size_t)MROWS * GK;
    unsigned short* blo = bhi + (size_t)GN * GK;
    float* s  = (float*)(blo + (size_t)GN * GK);
    float* h2 = s + (size_t)BATCH * GGRP * HID;

    conv_pack_kernel<<<4096, 256, 0, stream>>>((const float4*)x, cw, cb, ahi, alo);
    wpack_kernel    <<<512, 256, 0, stream>>>(w1, bhi, blo);
    gemm_scan_kernel<<<dim3(8, 64), 256, 0, stream>>>(ahi, alo, bhi, blo, b1, beta1, thr1, s);
    fc2_kernel      <<<256, 256, 0, stream>>>(s, w2, b2, h2);
    scan2_kernel    <<<1, 128, 0, stream>>>(h2, beta2, thr2, out);
}